// Round 14
// baseline (209.045 us; speedup 1.0000x reference)
//
#include <hip/hip_runtime.h>
#include <hip/hip_bf16.h>
#include <cstdint>
#include <cmath>

#define GG 128
#define SS 2048
#define LL 256
#define FF 512
#define DD 512

typedef __bf16 bf16_t;
typedef __bf16 bf16x8 __attribute__((ext_vector_type(8)));
typedef __bf16 bf16x4 __attribute__((ext_vector_type(4)));
typedef float  f32x4  __attribute__((ext_vector_type(4)));

#define MiB (1024UL * 1024UL)
// ---------------- workspace layout (~166 MiB peak) ----------------
#define OFF_INFO_HI (0 * MiB)     // bf16 [32768][512]
#define OFF_INFO_LO (32 * MiB)    // bf16 [32768][512]
#define OFF_T_HI    (64 * MiB)    // bf16 [32768][512]
#define OFF_T_LO    (96 * MiB)
#define OFF_S       (128 * MiB)   // fp32 [32768][256] (32 MiB)
#define OFF_WQ_HI   (160 * MiB)
#define OFF_WQ_LO   (160 * MiB + 512 * 1024)
#define OFF_WK_HI   (161 * MiB)
#define OFF_WK_LO   (161 * MiB + 512 * 1024)
#define OFF_GT_HI   (162 * MiB)
#define OFF_GT_LO   (162 * MiB + 512 * 1024)
#define OFF_VEFF    (163 * MiB)   // fp32 [32768]
#define OFF_VW      (164 * MiB)          // fp32 [512] vweff = Wv @ u
#define OFF_CC      (164 * MiB + 4096)   // fp32 [1] folded bias
#define OFF_U       (164 * MiB + 8192)   // fp32 [512]
#define OFF_V34     (164 * MiB + 12288)  // fp32 [128]
#define OFF_T2      (164 * MiB + 12800)  // fp32 [128]
#define OFF_V234    (164 * MiB + 13312)  // fp32 [256]
#define OFF_T3      (164 * MiB + 14336)  // fp32 [64]
#define OFF_WVEC    (165 * MiB)   // fp32 [32768]

// direct-to-LDS 16B load: wave-uniform LDS base + lane*16 implicit
__device__ __forceinline__ void gload16(const bf16_t* g, bf16_t* lds) {
  __builtin_amdgcn_global_load_lds(
      (const __attribute__((address_space(1))) void*)g,
      (__attribute__((address_space(3))) void*)lds, 16, 0, 0);
}

// ---------------------------------------------------------------------------
// merged prep: blocks [0,512) = Wq/Wk split cast;
//              blocks [512,640) = v34[r] = W3[r,:]@W4  (fold stage 1a)
//              blocks [640,768) = t2[c] = b1@W2[:,c] + b2[c] (fold stage 1b)
// ---------------------------------------------------------------------------
__global__ __launch_bounds__(256) void prep_fold1_kernel(
    const float* __restrict__ Wq, const float* __restrict__ Wk,
    const float* __restrict__ W3, const float* __restrict__ W4,
    const float* __restrict__ W2, const float* __restrict__ b1,
    const float* __restrict__ b2,
    bf16_t* __restrict__ Wq_hi, bf16_t* __restrict__ Wq_lo,
    bf16_t* __restrict__ Wk_hi, bf16_t* __restrict__ Wk_lo,
    float* __restrict__ v34, float* __restrict__ t2g) {
  const int b = blockIdx.x, t = threadIdx.x;
  if (b < 512) {
    const float* src = (b < 256) ? Wq : Wk;
    bf16_t* dhi = (b < 256) ? Wq_hi : Wk_hi;
    bf16_t* dlo = (b < 256) ? Wq_lo : Wk_lo;
    int i = (b & 255) * 256 + t;
    float4 v = *(const float4*)&src[(size_t)i * 4];
    float x[4] = {v.x, v.y, v.z, v.w};
    bf16x4 h, l;
#pragma unroll
    for (int e = 0; e < 4; ++e) {
      h[e] = (bf16_t)x[e];
      l[e] = (bf16_t)(x[e] - (float)h[e]);
    }
    *(bf16x4*)&dhi[(size_t)i * 4] = h;
    *(bf16x4*)&dlo[(size_t)i * 4] = l;
    return;
  }
  __shared__ float red[256];
  float acc = 0.f;
  if (b < 640) {  // v34 row-dot, K=64
    const int row = b - 512;
    for (int k = t; k < 64; k += 256) acc += W3[row * 64 + k] * W4[k];
  } else {        // t2 col-dot, K=256
    const int c = b - 640;
    for (int i = t; i < 256; i += 256) acc += b1[i] * W2[(size_t)i * 128 + c];
  }
  red[t] = acc;
  __syncthreads();
  if (t < 128) red[t] += red[t + 128];
  __syncthreads();
  if (t < 64) {
    float a = red[t] + red[t + 64];
#pragma unroll
    for (int off = 32; off > 0; off >>= 1) a += __shfl_down(a, off);
    if (t == 0) {
      if (b < 640) v34[b - 512] = a;
      else t2g[b - 640] = b2[b - 640] + a;
    }
  }
}

// ---------------------------------------------------------------------------
// generic fold stage: block-per-output-element, 256-thread tree reduce.
// ---------------------------------------------------------------------------
__global__ __launch_bounds__(256) void fold2_kernel(
    const float* __restrict__ M0, const float* __restrict__ v0,
    float* __restrict__ out0, int N0, int K0,
    const float* __restrict__ M1, const float* __restrict__ v1,
    const float* __restrict__ bias1, float* __restrict__ out1, int N1, int K1) {
  __shared__ float red[256];
  const int t = threadIdx.x;
  const int b = blockIdx.x;
  float acc = 0.f;
  if (b < N0) {
    const float* row = M0 + (size_t)b * K0;
    for (int k = t; k < K0; k += 256) acc += row[k] * v0[k];
  } else {
    const int c = b - N0;
    for (int i = t; i < K1; i += 256) acc += v1[i] * M1[(size_t)i * N1 + c];
  }
  red[t] = acc;
  __syncthreads();
  if (t < 128) red[t] += red[t + 128];
  __syncthreads();
  if (t < 64) {
    float a = red[t] + red[t + 64];
#pragma unroll
    for (int off = 32; off > 0; off >>= 1) a += __shfl_down(a, off);
    if (t == 0) {
      if (b < N0) out0[b] = a;
      else out1[b - N0] = bias1[b - N0] + a;
    }
  }
}

// ---------------------------------------------------------------------------
// fused info pass: hi/lo split + veff dot. Masked rows get explicit ZERO
// hi/lo rows (no info load) and veff=0 — deterministic, less read traffic.
// Wave per row.
// ---------------------------------------------------------------------------
__global__ __launch_bounds__(256) void cast_veff_kernel(
    const float* __restrict__ info, const float* __restrict__ vweff,
    const int* __restrict__ lengths, bf16_t* __restrict__ hi,
    bf16_t* __restrict__ lo, float* __restrict__ veff) {
  __shared__ float vw[512];
  const int t = threadIdx.x, lane = t & 63, wv = t >> 6;
  vw[t] = vweff[t];
  vw[256 + t] = vweff[256 + t];
  __syncthreads();
  const int row = blockIdx.x * 4 + wv;
  const int n = lengths[row >> 8];
  if ((row & 255) >= n) {
    bf16x8 z = {};
    *(bf16x8*)&hi[(size_t)row * 512 + lane * 8] = z;
    *(bf16x8*)&lo[(size_t)row * 512 + lane * 8] = z;
    if (lane == 0) veff[row] = 0.f;
    return;
  }
  const float* ip = info + (size_t)row * 512 + lane * 8;
  const float4 a = *(const float4*)ip;
  const float4 b = *(const float4*)(ip + 4);
  float x[8] = {a.x, a.y, a.z, a.w, b.x, b.y, b.z, b.w};
  bf16x8 h, l;
#pragma unroll
  for (int e = 0; e < 8; ++e) {
    h[e] = (bf16_t)x[e];
    l[e] = (bf16_t)(x[e] - (float)h[e]);
  }
  *(bf16x8*)&hi[(size_t)row * 512 + lane * 8] = h;
  *(bf16x8*)&lo[(size_t)row * 512 + lane * 8] = l;
  const int d0 = lane * 8;
  float acc = 0.f;
#pragma unroll
  for (int e = 0; e < 8; ++e) acc += x[e] * vw[d0 + e];
#pragma unroll
  for (int off = 32; off > 0; off >>= 1) acc += __shfl_down(acc, off);
  if (lane == 0) veff[row] = acc;
}

// ---------------------------------------------------------------------------
// gemm_bt2: dual-plane 3-term split GEMM with 2-phase software pipeline.
//   C[b] = Ahi@Bhi^T + Ahi@Blo^T + Alo@Bhi^T
// BM=128, BK=32, 256 threads (4 waves 2x2), MFMA 16x16x32.
// Double-buffered LDS (64 KB total -> 2 blocks/CU). Per step:
//   STAGE(next tile) issued BEFORE compute(cur); one vmcnt(0)+barrier per
//   step. MFMA order per 32-K-slice identical to proven kernel.
// PLANE STRIDE FIX (r13 NaN): As[buf][plane][PA] -> plane offset is PA,
// not 2*PA (2*PA is the BUFFER stride; writing there corrupted the other
// buffer and overflowed LDS for buf=1).
// Swizzle for 64B rows: slot ^= (r>>1)&3 on the gload SOURCE (rule 21).
// OUTMODE: 0 fp32, 2 split bf16. SKIP: 0 none; 1 global-M rows; 3 batched.
// ---------------------------------------------------------------------------
template <int BN, int OUTMODE, int SKIP, bool SWIZ>
__global__ __launch_bounds__(256) void gemm_bt2(
    const bf16_t* __restrict__ Ahi, const bf16_t* __restrict__ Alo, int lda, long sA,
    const bf16_t* __restrict__ Bhi, const bf16_t* __restrict__ Blo, int ldb, long sB,
    void* __restrict__ C0, void* __restrict__ C1, int ldc, long sC,
    int K, const int* __restrict__ lengths) {
  constexpr int BM = 128;
  constexpr int BK = 32;
  constexpr int WM = 4;
  constexpr int WN = BN / 32;          // 4
  constexpr int PA = BM * BK;          // elems / plane / buf
  constexpr int PB = BN * BK;
  __shared__ bf16_t As[2][2][PA];      // [buf][plane]
  __shared__ bf16_t Bs[2][2][PB];

  const int gx = gridDim.x, gy = gridDim.y;
  int wgid = blockIdx.x + gx * (blockIdx.y + gy * blockIdx.z);
  if (SWIZ) {
    const int nwg = gx * gy * (int)gridDim.z;
    const int q = nwg >> 3;
    wgid = (wgid & 7) * q + (wgid >> 3);
  }
  const int xx = wgid % gx;
  const int rem = wgid / gx;
  const int yy = rem % gy;
  const int b = rem / gy;
  const int m0 = yy * BM;
  const int n0 = xx * BN;

  if (SKIP == 1) { if ((m0 & 255) >= lengths[m0 >> 8]) return; }
  if (SKIP == 3) { int n = lengths[b]; if (m0 >= n || n0 >= n) return; }

  const int t = threadIdx.x;
  const int lane = t & 63;
  const int wave = t >> 6;
  const int wm = (wave >> 1) * 64;
  const int wn = (wave & 1) * (BN / 2);

  const bf16_t* Ah = Ahi + (size_t)b * sA;
  const bf16_t* Al = Alo + (size_t)b * sA;
  const bf16_t* Bh = Bhi + (size_t)b * sB;
  const bf16_t* Bl = Blo + (size_t)b * sB;

  f32x4 acc[WM][WN];
#pragma unroll
  for (int i = 0; i < WM; ++i)
#pragma unroll
    for (int j = 0; j < WN; ++j) acc[i][j] = {0.f, 0.f, 0.f, 0.f};

  const int fr = lane & 15;
  const int fs = lane >> 4;            // k-slot 0..3 (exactly BK/8)
  const int sr = t >> 2, ssl = t & 3;  // staging: chunk row / slot

  const int nsteps = K / BK;

  // prologue: stage step 0 into buf 0
  {
#pragma unroll
    for (int it = 0; it < BM / 64; ++it) {
      const int r = sr + it * 64;
      const size_t ga = (size_t)(m0 + r) * lda + ((ssl ^ ((r >> 1) & 3)) << 3);
      bf16_t* dst = &As[0][0][(it * 256 + wave * 64) * 8];
      gload16(&Ah[ga], dst);
      gload16(&Al[ga], dst + PA);  // plane stride = PA
    }
#pragma unroll
    for (int it = 0; it < BN / 64; ++it) {
      const int r = sr + it * 64;
      const size_t ga = (size_t)(n0 + r) * ldb + ((ssl ^ ((r >> 1) & 3)) << 3);
      bf16_t* dst = &Bs[0][0][(it * 256 + wave * 64) * 8];
      gload16(&Bh[ga], dst);
      gload16(&Bl[ga], dst + PB);
    }
  }
  asm volatile("s_waitcnt vmcnt(0)" ::: "memory");
  __builtin_amdgcn_sched_barrier(0);
  __syncthreads();

#pragma unroll 2
  for (int s = 0; s < nsteps; ++s) {
    const int cur = s & 1;
    // issue next-tile staging BEFORE compute (latency hides under MFMAs)
    if (s + 1 < nsteps) {
      const int k0 = (s + 1) * BK;
      const int nxt = (s + 1) & 1;
#pragma unroll
      for (int it = 0; it < BM / 64; ++it) {
        const int r = sr + it * 64;
        const size_t ga = (size_t)(m0 + r) * lda + k0 + ((ssl ^ ((r >> 1) & 3)) << 3);
        bf16_t* dst = &As[nxt][0][(it * 256 + wave * 64) * 8];
        gload16(&Ah[ga], dst);
        gload16(&Al[ga], dst + PA);
      }
#pragma unroll
      for (int it = 0; it < BN / 64; ++it) {
        const int r = sr + it * 64;
        const size_t ga = (size_t)(n0 + r) * ldb + k0 + ((ssl ^ ((r >> 1) & 3)) << 3);
        bf16_t* dst = &Bs[nxt][0][(it * 256 + wave * 64) * 8];
        gload16(&Bh[ga], dst);
        gload16(&Bl[ga], dst + PB);
      }
    }
    // compute current buffer (3-term, order identical to proven kernel)
    bf16x8 ah[WM], al[WM], bh[WN], bl[WN];
#pragma unroll
    for (int i = 0; i < WM; ++i) {
      int r = wm + i * 16 + fr;
      int la = r * BK + ((fs ^ ((r >> 1) & 3)) * 8);
      ah[i] = *(const bf16x8*)&As[cur][0][la];
      al[i] = *(const bf16x8*)&As[cur][1][la];
    }
#pragma unroll
    for (int j = 0; j < WN; ++j) {
      int r = wn + j * 16 + fr;
      int la = r * BK + ((fs ^ ((r >> 1) & 3)) * 8);
      bh[j] = *(const bf16x8*)&Bs[cur][0][la];
      bl[j] = *(const bf16x8*)&Bs[cur][1][la];
    }
#pragma unroll
    for (int i = 0; i < WM; ++i)
#pragma unroll
      for (int j = 0; j < WN; ++j) {
        acc[i][j] = __builtin_amdgcn_mfma_f32_16x16x32_bf16(ah[i], bh[j], acc[i][j], 0, 0, 0);
        acc[i][j] = __builtin_amdgcn_mfma_f32_16x16x32_bf16(ah[i], bl[j], acc[i][j], 0, 0, 0);
        acc[i][j] = __builtin_amdgcn_mfma_f32_16x16x32_bf16(al[i], bh[j], acc[i][j], 0, 0, 0);
      }
    // drain next-tile staging + release current buffer for overwrite
    asm volatile("s_waitcnt vmcnt(0)" ::: "memory");
    __builtin_amdgcn_sched_barrier(0);
    __syncthreads();
  }

#pragma unroll
  for (int i = 0; i < WM; ++i) {
#pragma unroll
    for (int j = 0; j < WN; ++j) {
      const int col = n0 + wn + j * 16 + fr;
#pragma unroll
      for (int jj = 0; jj < 4; ++jj) {
        const int row = m0 + wm + i * 16 + fs * 4 + jj;
        const float v = acc[i][j][jj];
        const size_t off = (size_t)b * sC + (size_t)row * ldc + col;
        if (OUTMODE == 0) {
          ((float*)C0)[off] = v;
        } else {
          bf16_t h = (bf16_t)v;
          ((bf16_t*)C0)[off] = h;
          ((bf16_t*)C1)[off] = (bf16_t)(v - (float)h);
        }
      }
    }
  }
}

// ---------------------------------------------------------------------------
// fused masked softmax + scorer: w[row] = sum(exp(S-m)*veff)/sum(exp) + c0,
// with length==1 onehot and masking. One wave per row; all w written.
// ---------------------------------------------------------------------------
__global__ __launch_bounds__(256) void softmax_dot_kernel(
    const float* __restrict__ S, const float* __restrict__ veff,
    const float* __restrict__ cc, const int* __restrict__ lengths,
    float* __restrict__ w) {
  const int t = threadIdx.x, lane = t & 63, wave = t >> 6;
  const int row = blockIdx.x * 4 + wave;
  const int g = row >> 8, l = row & 255;
  const int n = lengths[g];
  if (n == 1 || l >= n) {
    if (lane == 0) w[row] = (n == 1 && l == 0) ? 1.f : 0.f;
    return;
  }
  const float* srow = S + (size_t)row * 256;
  const int c0i = lane * 4;
  float4 v = *(const float4*)&srow[c0i];
  float4 vf = *(const float4*)&veff[g * 256 + c0i];
  float s[4] = {v.x, v.y, v.z, v.w};
  float ve[4] = {vf.x, vf.y, vf.z, vf.w};
  float m = -INFINITY;
#pragma unroll
  for (int e = 0; e < 4; ++e)
    if (c0i + e < n) m = fmaxf(m, s[e]);
#pragma unroll
  for (int off = 32; off > 0; off >>= 1) m = fmaxf(m, __shfl_xor(m, off));
  float sum = 0.f, dot = 0.f;
#pragma unroll
  for (int e = 0; e < 4; ++e) {
    if (c0i + e < n) {
      float ee = __expf(s[e] - m);
      sum += ee;
      dot += ee * ve[e];
    }
  }
#pragma unroll
  for (int off = 32; off > 0; off >>= 1) {
    sum += __shfl_xor(sum, off);
    dot += __shfl_xor(dot, off);
  }
  if (lane == 0) w[row] = dot / sum + cc[0];
}

// ---------------------------------------------------------------------------
// out[s,g] = sum_l raw[g,s,l] * w[g,l]; skips l >= n (w is exactly 0 there)
// ---------------------------------------------------------------------------
__global__ __launch_bounds__(256) void out_kernel(
    const float* __restrict__ raw, const float* __restrict__ w,
    const int* __restrict__ lengths, float* __restrict__ out) {
  __shared__ float wl[LL];
  const int g = blockIdx.x;
  const int t = threadIdx.x;
  wl[t] = w[g * LL + t];
  __syncthreads();
  const int n = lengths[g];
  const int wave = t >> 6, lane = t & 63;
  const int s = blockIdx.y * 4 + wave;
  float acc = 0.f;
  if (lane * 4 < n) {
    const float4 r4 = *(const float4*)(raw + ((size_t)g * SS + s) * LL + lane * 4);
    const float4 w4v = *(const float4*)&wl[lane * 4];
    acc = r4.x * w4v.x + r4.y * w4v.y + r4.z * w4v.z + r4.w * w4v.w;
  }
#pragma unroll
  for (int off = 32; off > 0; off >>= 1) acc += __shfl_down(acc, off);
  if (lane == 0) out[(size_t)s * GG + g] = acc;
}

// ---------------------------------------------------------------------------
extern "C" void kernel_launch(void* const* d_in, const int* in_sizes, int n_in,
                              void* d_out, int out_size, void* d_ws, size_t ws_size,
                              hipStream_t stream) {
  const float* raw  = (const float*)d_in[0];
  const float* info = (const float*)d_in[1];
  const float* Wq   = (const float*)d_in[2];
  const float* Wk   = (const float*)d_in[3];
  const float* Wv   = (const float*)d_in[4];
  const float* W1   = (const float*)d_in[5];
  const float* b1   = (const float*)d_in[6];
  const float* W2   = (const float*)d_in[7];
  const float* b2   = (const float*)d_in[8];
  const float* W3   = (const float*)d_in[9];
  const float* b3   = (const float*)d_in[10];
  const float* W4   = (const float*)d_in[11];
  const float* b4   = (const float*)d_in[12];
  const int* lengths = (const int*)d_in[13];
  float* out = (float*)d_out;

  char* ws = (char*)d_ws;
  bf16_t* info_hi = (bf16_t*)(ws + OFF_INFO_HI);
  bf16_t* info_lo = (bf16_t*)(ws + OFF_INFO_LO);
  bf16_t* T_hi = (bf16_t*)(ws + OFF_T_HI);
  bf16_t* T_lo = (bf16_t*)(ws + OFF_T_LO);
  bf16_t* Wq_hi = (bf16_t*)(ws + OFF_WQ_HI);
  bf16_t* Wq_lo = (bf16_t*)(ws + OFF_WQ_LO);
  bf16_t* Wk_hi = (bf16_t*)(ws + OFF_WK_HI);
  bf16_t* Wk_lo = (bf16_t*)(ws + OFF_WK_LO);
  bf16_t* Gt_hi = (bf16_t*)(ws + OFF_GT_HI);
  bf16_t* Gt_lo = (bf16_t*)(ws + OFF_GT_LO);
  float*  S     = (float*)(ws + OFF_S);
  float*  veff  = (float*)(ws + OFF_VEFF);
  float*  vweff = (float*)(ws + OFF_VW);
  float*  cc    = (float*)(ws + OFF_CC);
  float*  u_g   = (float*)(ws + OFF_U);
  float*  v34   = (float*)(ws + OFF_V34);
  float*  t2g   = (float*)(ws + OFF_T2);
  float*  v234  = (float*)(ws + OFF_V234);
  float*  t3g   = (float*)(ws + OFF_T3);
  float*  w     = (float*)(ws + OFF_WVEC);

  dim3 blk(256);
  const int M = GG * LL;  // 32768

  // merged prep: Wq/Wk split cast + fold stage 1 (v34, t2)
  prep_fold1_kernel<<<dim3(768), blk, 0, stream>>>(
      Wq, Wk, W3, W4, W2, b1, b2, Wq_hi, Wq_lo, Wk_hi, Wk_lo, v34, t2g);

  // fold stages 2-4
  fold2_kernel<<<dim3(320), blk, 0, stream>>>(
      W2, v34, v234, 256, 128, W3, t2g, b3, t3g, 64, 128);
  fold2_kernel<<<dim3(513), blk, 0, stream>>>(
      W1, v234, u_g, 512, 256, W4, t3g, b4, cc, 1, 64);
  fold2_kernel<<<dim3(512), blk, 0, stream>>>(
      Wv, u_g, vweff, 512, 512, W4, t3g, b4, cc, 0, 64);

  // fused info pass: hi/lo split + veff in one read of info
  cast_veff_kernel<<<dim3(M / 4), blk, 0, stream>>>(info, vweff, lengths,
                                                    info_hi, info_lo, veff);

  // Gt = Wk @ Wq^T (dual-plane 3-term split) so that Gt^T = G = Wq @ Wk^T
  gemm_bt2<128, 2, 0, false><<<dim3(4, 4, 1), blk, 0, stream>>>(
      Wk_hi, Wk_lo, 512, 0, Wq_hi, Wq_lo, 512, 0, Gt_hi, Gt_lo, 512, 0, 512, nullptr);

  // T = info @ G (dual-plane split out), skip masked row blocks, XCD-swizzled
  gemm_bt2<128, 2, 1, true><<<dim3(4, M / 128, 1), blk, 0, stream>>>(
      info_hi, info_lo, 512, 0, Gt_hi, Gt_lo, 512, 0, T_hi, T_lo, 512, 0, 512, lengths);

  // S[g] = T[g] @ info[g]^T (3-term split -> fp32), tile-skipped, swizzled
  gemm_bt2<128, 0, 3, true><<<dim3(2, 2, GG), blk, 0, stream>>>(
      T_hi, T_lo, 512, 256L * 512, info_hi, info_lo, 512, 256L * 512,
      S, nullptr, 256, 256L * 256, 512, lengths);

  // fused softmax + scorer -> w
  softmax_dot_kernel<<<dim3(M / 4), blk, 0, stream>>>(S, veff, cc, lengths, w);

  // out = einsum('gsl,gl->sg')
  out_kernel<<<dim3(GG, SS / 4), blk, 0, stream>>>(raw, w, lengths, out);
}

// Round 15
// 170.367 us; speedup vs baseline: 1.2270x; 1.2270x over previous
//
#include <hip/hip_runtime.h>
#include <hip/hip_bf16.h>
#include <cstdint>
#include <cmath>

#define GG 128
#define SS 2048
#define LL 256
#define FF 512
#define DD 512

typedef __bf16 bf16_t;
typedef __bf16 bf16x8 __attribute__((ext_vector_type(8)));
typedef __bf16 bf16x4 __attribute__((ext_vector_type(4)));
typedef float  f32x4  __attribute__((ext_vector_type(4)));

#define MiB (1024UL * 1024UL)
// ---------------- workspace layout (~166 MiB peak) ----------------
#define OFF_INFO_HI (0 * MiB)     // bf16 [32768][512]
#define OFF_INFO_LO (32 * MiB)    // bf16 [32768][512]
#define OFF_T_HI    (64 * MiB)    // bf16 [32768][512]
#define OFF_T_LO    (96 * MiB)
#define OFF_S       (128 * MiB)   // fp32 [32768][256] (32 MiB)
#define OFF_WQ_HI   (160 * MiB)
#define OFF_WQ_LO   (160 * MiB + 512 * 1024)
#define OFF_WK_HI   (161 * MiB)
#define OFF_WK_LO   (161 * MiB + 512 * 1024)
#define OFF_GT_HI   (162 * MiB)
#define OFF_GT_LO   (162 * MiB + 512 * 1024)
#define OFF_VEFF    (163 * MiB)   // fp32 [32768]
#define OFF_VW      (164 * MiB)          // fp32 [512] vweff = Wv @ u
#define OFF_CC      (164 * MiB + 4096)   // fp32 [1] folded bias
#define OFF_U       (164 * MiB + 8192)   // fp32 [512]
#define OFF_V34     (164 * MiB + 12288)  // fp32 [128]
#define OFF_T2      (164 * MiB + 12800)  // fp32 [128]
#define OFF_V234    (164 * MiB + 13312)  // fp32 [256]
#define OFF_T3      (164 * MiB + 14336)  // fp32 [64]
#define OFF_WVEC    (165 * MiB)   // fp32 [32768]

// direct-to-LDS 16B load: wave-uniform LDS base + lane*16 implicit
__device__ __forceinline__ void gload16(const bf16_t* g, bf16_t* lds) {
  __builtin_amdgcn_global_load_lds(
      (const __attribute__((address_space(1))) void*)g,
      (__attribute__((address_space(3))) void*)lds, 16, 0, 0);
}

// ---------------------------------------------------------------------------
// merged prep: blocks [0,512) = Wq/Wk split cast;
//              blocks [512,640) = v34[r] = W3[r,:]@W4  (fold stage 1a)
//              blocks [640,768) = t2[c] = b1@W2[:,c] + b2[c] (fold stage 1b)
// ---------------------------------------------------------------------------
__global__ __launch_bounds__(256) void prep_fold1_kernel(
    const float* __restrict__ Wq, const float* __restrict__ Wk,
    const float* __restrict__ W3, const float* __restrict__ W4,
    const float* __restrict__ W2, const float* __restrict__ b1,
    const float* __restrict__ b2,
    bf16_t* __restrict__ Wq_hi, bf16_t* __restrict__ Wq_lo,
    bf16_t* __restrict__ Wk_hi, bf16_t* __restrict__ Wk_lo,
    float* __restrict__ v34, float* __restrict__ t2g) {
  const int b = blockIdx.x, t = threadIdx.x;
  if (b < 512) {
    const float* src = (b < 256) ? Wq : Wk;
    bf16_t* dhi = (b < 256) ? Wq_hi : Wk_hi;
    bf16_t* dlo = (b < 256) ? Wq_lo : Wk_lo;
    int i = (b & 255) * 256 + t;
    float4 v = *(const float4*)&src[(size_t)i * 4];
    float x[4] = {v.x, v.y, v.z, v.w};
    bf16x4 h, l;
#pragma unroll
    for (int e = 0; e < 4; ++e) {
      h[e] = (bf16_t)x[e];
      l[e] = (bf16_t)(x[e] - (float)h[e]);
    }
    *(bf16x4*)&dhi[(size_t)i * 4] = h;
    *(bf16x4*)&dlo[(size_t)i * 4] = l;
    return;
  }
  __shared__ float red[256];
  float acc = 0.f;
  if (b < 640) {  // v34 row-dot, K=64
    const int row = b - 512;
    for (int k = t; k < 64; k += 256) acc += W3[row * 64 + k] * W4[k];
  } else {        // t2 col-dot, K=256
    const int c = b - 640;
    for (int i = t; i < 256; i += 256) acc += b1[i] * W2[(size_t)i * 128 + c];
  }
  red[t] = acc;
  __syncthreads();
  if (t < 128) red[t] += red[t + 128];
  __syncthreads();
  if (t < 64) {
    float a = red[t] + red[t + 64];
#pragma unroll
    for (int off = 32; off > 0; off >>= 1) a += __shfl_down(a, off);
    if (t == 0) {
      if (b < 640) v34[b - 512] = a;
      else t2g[b - 640] = b2[b - 640] + a;
    }
  }
}

// ---------------------------------------------------------------------------
// generic fold stage: block-per-output-element, 256-thread tree reduce.
// ---------------------------------------------------------------------------
__global__ __launch_bounds__(256) void fold2_kernel(
    const float* __restrict__ M0, const float* __restrict__ v0,
    float* __restrict__ out0, int N0, int K0,
    const float* __restrict__ M1, const float* __restrict__ v1,
    const float* __restrict__ bias1, float* __restrict__ out1, int N1, int K1) {
  __shared__ float red[256];
  const int t = threadIdx.x;
  const int b = blockIdx.x;
  float acc = 0.f;
  if (b < N0) {
    const float* row = M0 + (size_t)b * K0;
    for (int k = t; k < K0; k += 256) acc += row[k] * v0[k];
  } else {
    const int c = b - N0;
    for (int i = t; i < K1; i += 256) acc += v1[i] * M1[(size_t)i * N1 + c];
  }
  red[t] = acc;
  __syncthreads();
  if (t < 128) red[t] += red[t + 128];
  __syncthreads();
  if (t < 64) {
    float a = red[t] + red[t + 64];
#pragma unroll
    for (int off = 32; off > 0; off >>= 1) a += __shfl_down(a, off);
    if (t == 0) {
      if (b < N0) out0[b] = a;
      else out1[b - N0] = bias1[b - N0] + a;
    }
  }
}

// ---------------------------------------------------------------------------
// fused info pass: hi/lo split + veff dot. Masked rows get explicit ZERO
// hi/lo rows (no info load) and veff=0 — deterministic, less read traffic.
// (validated in r14 run) Wave per row.
// ---------------------------------------------------------------------------
__global__ __launch_bounds__(256) void cast_veff_kernel(
    const float* __restrict__ info, const float* __restrict__ vweff,
    const int* __restrict__ lengths, bf16_t* __restrict__ hi,
    bf16_t* __restrict__ lo, float* __restrict__ veff) {
  __shared__ float vw[512];
  const int t = threadIdx.x, lane = t & 63, wv = t >> 6;
  vw[t] = vweff[t];
  vw[256 + t] = vweff[256 + t];
  __syncthreads();
  const int row = blockIdx.x * 4 + wv;
  const int n = lengths[row >> 8];
  if ((row & 255) >= n) {
    bf16x8 z = {};
    *(bf16x8*)&hi[(size_t)row * 512 + lane * 8] = z;
    *(bf16x8*)&lo[(size_t)row * 512 + lane * 8] = z;
    if (lane == 0) veff[row] = 0.f;
    return;
  }
  const float* ip = info + (size_t)row * 512 + lane * 8;
  const float4 a = *(const float4*)ip;
  const float4 b = *(const float4*)(ip + 4);
  float x[8] = {a.x, a.y, a.z, a.w, b.x, b.y, b.z, b.w};
  bf16x8 h, l;
#pragma unroll
  for (int e = 0; e < 8; ++e) {
    h[e] = (bf16_t)x[e];
    l[e] = (bf16_t)(x[e] - (float)h[e]);
  }
  *(bf16x8*)&hi[(size_t)row * 512 + lane * 8] = h;
  *(bf16x8*)&lo[(size_t)row * 512 + lane * 8] = l;
  const int d0 = lane * 8;
  float acc = 0.f;
#pragma unroll
  for (int e = 0; e < 8; ++e) acc += x[e] * vw[d0 + e];
#pragma unroll
  for (int off = 32; off > 0; off >>= 1) acc += __shfl_down(acc, off);
  if (lane == 0) veff[row] = acc;
}

// ---------------------------------------------------------------------------
// gemm_bt (r9/r12 proven, 200.8us config): C[b] = A[b] @ Bt[b]^T,
// dual-plane 3-term split. BM=128, BK=64, 256 threads (4 waves 2x2),
// MFMA 16x16x32, single-buffer LDS (2 blocks/CU), global_load_lds staging,
// XOR swizzle on SOURCE (rule 21), explicit vmcnt drain before barrier.
// SWIZ: XCD-chunked remap (nwg % 8 == 0).
// OUTMODE: 0 fp32, 2 split bf16. SKIP: 0 none; 1 global-M rows; 3 batched.
// ---------------------------------------------------------------------------
template <int BN, bool ASPLIT, bool BSPLIT, int OUTMODE, int SKIP, bool SWIZ>
__global__ __launch_bounds__(256) void gemm_bt(
    const bf16_t* __restrict__ Ahi, const bf16_t* __restrict__ Alo, int lda, long sA,
    const bf16_t* __restrict__ Bhi, const bf16_t* __restrict__ Blo, int ldb, long sB,
    void* __restrict__ C0, void* __restrict__ C1, int ldc, long sC,
    int K, const int* __restrict__ lengths) {
  constexpr int BM = 128;
  constexpr int BK = 64;
  constexpr int WM = 4;
  constexpr int WN = BN / 32;
  constexpr int PA = BM * BK;
  constexpr int PB = BN * BK;
  constexpr int ITA = BM * 8 / 256;
  constexpr int ITB = BN * 8 / 256;
  __shared__ bf16_t As[(ASPLIT ? 2 : 1) * PA];
  __shared__ bf16_t Bs[(BSPLIT ? 2 : 1) * PB];

  const int gx = gridDim.x, gy = gridDim.y;
  int wgid = blockIdx.x + gx * (blockIdx.y + gy * blockIdx.z);
  if (SWIZ) {
    const int nwg = gx * gy * (int)gridDim.z;
    const int q = nwg >> 3;
    wgid = (wgid & 7) * q + (wgid >> 3);
  }
  const int xx = wgid % gx;
  const int rem = wgid / gx;
  const int yy = rem % gy;
  const int b = rem / gy;
  const int m0 = yy * BM;
  const int n0 = xx * BN;

  if (SKIP == 1) { if ((m0 & 255) >= lengths[m0 >> 8]) return; }
  if (SKIP == 3) { int n = lengths[b]; if (m0 >= n || n0 >= n) return; }

  const int t = threadIdx.x;
  const int lane = t & 63;
  const int wave = t >> 6;
  const int wm = (wave >> 1) * 64;
  const int wn = (wave & 1) * (BN / 2);

  const bf16_t* Ah = Ahi + (size_t)b * sA;
  const bf16_t* Al = ASPLIT ? Alo + (size_t)b * sA : nullptr;
  const bf16_t* Bh = Bhi + (size_t)b * sB;
  const bf16_t* Bl = BSPLIT ? Blo + (size_t)b * sB : nullptr;

  f32x4 acc[WM][WN];
#pragma unroll
  for (int i = 0; i < WM; ++i)
#pragma unroll
    for (int j = 0; j < WN; ++j) acc[i][j] = {0.f, 0.f, 0.f, 0.f};

  const int fr = lane & 15;
  const int fs = lane >> 4;
  const int sr = t >> 3, ssl = t & 7;

  for (int k0 = 0; k0 < K; k0 += BK) {
#pragma unroll
    for (int it = 0; it < ITA; ++it) {
      const int r = sr + it * 32;
      const size_t ga = (size_t)(m0 + r) * lda + k0 + ((ssl ^ (r & 7)) << 3);
      bf16_t* dst = &As[(it * 256 + wave * 64) * 8];
      gload16(&Ah[ga], dst);
      if (ASPLIT) gload16(&Al[ga], dst + PA);
    }
#pragma unroll
    for (int it = 0; it < ITB; ++it) {
      const int r = sr + it * 32;
      const size_t ga = (size_t)(n0 + r) * ldb + k0 + ((ssl ^ (r & 7)) << 3);
      bf16_t* dst = &Bs[(it * 256 + wave * 64) * 8];
      gload16(&Bh[ga], dst);
      if (BSPLIT) gload16(&Bl[ga], dst + PB);
    }
    asm volatile("s_waitcnt vmcnt(0)" ::: "memory");
    __builtin_amdgcn_sched_barrier(0);
    __syncthreads();
#pragma unroll
    for (int kk = 0; kk < 2; ++kk) {
      bf16x8 ah[WM], al[WM], bh[WN], bl[WN];
#pragma unroll
      for (int i = 0; i < WM; ++i) {
        int r = wm + i * 16 + fr;
        int la = r * BK + (((kk * 4 + fs) ^ (r & 7)) * 8);
        ah[i] = *(const bf16x8*)&As[la];
        if (ASPLIT) al[i] = *(const bf16x8*)&As[PA + la];
      }
#pragma unroll
      for (int j = 0; j < WN; ++j) {
        int r = wn + j * 16 + fr;
        int la = r * BK + (((kk * 4 + fs) ^ (r & 7)) * 8);
        bh[j] = *(const bf16x8*)&Bs[la];
        if (BSPLIT) bl[j] = *(const bf16x8*)&Bs[PB + la];
      }
#pragma unroll
      for (int i = 0; i < WM; ++i)
#pragma unroll
        for (int j = 0; j < WN; ++j) {
          acc[i][j] = __builtin_amdgcn_mfma_f32_16x16x32_bf16(ah[i], bh[j], acc[i][j], 0, 0, 0);
          if (BSPLIT)
            acc[i][j] = __builtin_amdgcn_mfma_f32_16x16x32_bf16(ah[i], bl[j], acc[i][j], 0, 0, 0);
          if (ASPLIT)
            acc[i][j] = __builtin_amdgcn_mfma_f32_16x16x32_bf16(al[i], bh[j], acc[i][j], 0, 0, 0);
        }
    }
    __syncthreads();
  }

#pragma unroll
  for (int i = 0; i < WM; ++i) {
#pragma unroll
    for (int j = 0; j < WN; ++j) {
      const int col = n0 + wn + j * 16 + fr;
#pragma unroll
      for (int jj = 0; jj < 4; ++jj) {
        const int row = m0 + wm + i * 16 + fs * 4 + jj;
        const float v = acc[i][j][jj];
        const size_t off = (size_t)b * sC + (size_t)row * ldc + col;
        if (OUTMODE == 0) {
          ((float*)C0)[off] = v;
        } else {
          bf16_t h = (bf16_t)v;
          ((bf16_t*)C0)[off] = h;
          ((bf16_t*)C1)[off] = (bf16_t)(v - (float)h);
        }
      }
    }
  }
}

// ---------------------------------------------------------------------------
// fused masked softmax + scorer: w[row] = sum(exp(S-m)*veff)/sum(exp) + c0,
// with length==1 onehot and masking. One wave per row; all w written.
// ---------------------------------------------------------------------------
__global__ __launch_bounds__(256) void softmax_dot_kernel(
    const float* __restrict__ S, const float* __restrict__ veff,
    const float* __restrict__ cc, const int* __restrict__ lengths,
    float* __restrict__ w) {
  const int t = threadIdx.x, lane = t & 63, wave = t >> 6;
  const int row = blockIdx.x * 4 + wave;
  const int g = row >> 8, l = row & 255;
  const int n = lengths[g];
  if (n == 1 || l >= n) {
    if (lane == 0) w[row] = (n == 1 && l == 0) ? 1.f : 0.f;
    return;
  }
  const float* srow = S + (size_t)row * 256;
  const int c0i = lane * 4;
  float4 v = *(const float4*)&srow[c0i];
  float4 vf = *(const float4*)&veff[g * 256 + c0i];
  float s[4] = {v.x, v.y, v.z, v.w};
  float ve[4] = {vf.x, vf.y, vf.z, vf.w};
  float m = -INFINITY;
#pragma unroll
  for (int e = 0; e < 4; ++e)
    if (c0i + e < n) m = fmaxf(m, s[e]);
#pragma unroll
  for (int off = 32; off > 0; off >>= 1) m = fmaxf(m, __shfl_xor(m, off));
  float sum = 0.f, dot = 0.f;
#pragma unroll
  for (int e = 0; e < 4; ++e) {
    if (c0i + e < n) {
      float ee = __expf(s[e] - m);
      sum += ee;
      dot += ee * ve[e];
    }
  }
#pragma unroll
  for (int off = 32; off > 0; off >>= 1) {
    sum += __shfl_xor(sum, off);
    dot += __shfl_xor(dot, off);
  }
  if (lane == 0) w[row] = dot / sum + cc[0];
}

// ---------------------------------------------------------------------------
// out[s,g] = sum_l raw[g,s,l] * w[g,l]; skips l >= n (w is exactly 0 there).
// 16 samples per block (4 per wave) to amortize the LDS w-row load.
// ---------------------------------------------------------------------------
__global__ __launch_bounds__(256) void out_kernel(
    const float* __restrict__ raw, const float* __restrict__ w,
    const int* __restrict__ lengths, float* __restrict__ out) {
  __shared__ float wl[LL];
  const int g = blockIdx.x;
  const int t = threadIdx.x;
  wl[t] = w[g * LL + t];
  __syncthreads();
  const int n = lengths[g];
  const int wave = t >> 6, lane = t & 63;
  const bool act = lane * 4 < n;
  float4 w4v = make_float4(0.f, 0.f, 0.f, 0.f);
  if (act) w4v = *(const float4*)&wl[lane * 4];
  const int s0 = blockIdx.y * 16 + wave * 4;
#pragma unroll
  for (int e = 0; e < 4; ++e) {
    const int s = s0 + e;
    float acc = 0.f;
    if (act) {
      const float4 r4 = *(const float4*)(raw + ((size_t)g * SS + s) * LL + lane * 4);
      acc = r4.x * w4v.x + r4.y * w4v.y + r4.z * w4v.z + r4.w * w4v.w;
    }
#pragma unroll
    for (int off = 32; off > 0; off >>= 1) acc += __shfl_down(acc, off);
    if (lane == 0) out[(size_t)s * GG + g] = acc;
  }
}

// ---------------------------------------------------------------------------
extern "C" void kernel_launch(void* const* d_in, const int* in_sizes, int n_in,
                              void* d_out, int out_size, void* d_ws, size_t ws_size,
                              hipStream_t stream) {
  const float* raw  = (const float*)d_in[0];
  const float* info = (const float*)d_in[1];
  const float* Wq   = (const float*)d_in[2];
  const float* Wk   = (const float*)d_in[3];
  const float* Wv   = (const float*)d_in[4];
  const float* W1   = (const float*)d_in[5];
  const float* b1   = (const float*)d_in[6];
  const float* W2   = (const float*)d_in[7];
  const float* b2   = (const float*)d_in[8];
  const float* W3   = (const float*)d_in[9];
  const float* b3   = (const float*)d_in[10];
  const float* W4   = (const float*)d_in[11];
  const float* b4   = (const float*)d_in[12];
  const int* lengths = (const int*)d_in[13];
  float* out = (float*)d_out;

  char* ws = (char*)d_ws;
  bf16_t* info_hi = (bf16_t*)(ws + OFF_INFO_HI);
  bf16_t* info_lo = (bf16_t*)(ws + OFF_INFO_LO);
  bf16_t* T_hi = (bf16_t*)(ws + OFF_T_HI);
  bf16_t* T_lo = (bf16_t*)(ws + OFF_T_LO);
  bf16_t* Wq_hi = (bf16_t*)(ws + OFF_WQ_HI);
  bf16_t* Wq_lo = (bf16_t*)(ws + OFF_WQ_LO);
  bf16_t* Wk_hi = (bf16_t*)(ws + OFF_WK_HI);
  bf16_t* Wk_lo = (bf16_t*)(ws + OFF_WK_LO);
  bf16_t* Gt_hi = (bf16_t*)(ws + OFF_GT_HI);
  bf16_t* Gt_lo = (bf16_t*)(ws + OFF_GT_LO);
  float*  S     = (float*)(ws + OFF_S);
  float*  veff  = (float*)(ws + OFF_VEFF);
  float*  vweff = (float*)(ws + OFF_VW);
  float*  cc    = (float*)(ws + OFF_CC);
  float*  u_g   = (float*)(ws + OFF_U);
  float*  v34   = (float*)(ws + OFF_V34);
  float*  t2g   = (float*)(ws + OFF_T2);
  float*  v234  = (float*)(ws + OFF_V234);
  float*  t3g   = (float*)(ws + OFF_T3);
  float*  w     = (float*)(ws + OFF_WVEC);

  dim3 blk(256);
  const int M = GG * LL;  // 32768

  // merged prep: Wq/Wk split cast + fold stage 1 (v34, t2)
  prep_fold1_kernel<<<dim3(768), blk, 0, stream>>>(
      Wq, Wk, W3, W4, W2, b1, b2, Wq_hi, Wq_lo, Wk_hi, Wk_lo, v34, t2g);

  // fold stages 2-4
  fold2_kernel<<<dim3(320), blk, 0, stream>>>(
      W2, v34, v234, 256, 128, W3, t2g, b3, t3g, 64, 128);
  fold2_kernel<<<dim3(513), blk, 0, stream>>>(
      W1, v234, u_g, 512, 256, W4, t3g, b4, cc, 1, 64);
  fold2_kernel<<<dim3(512), blk, 0, stream>>>(
      Wv, u_g, vweff, 512, 512, W4, t3g, b4, cc, 0, 64);

  // fused info pass: hi/lo split + veff in one read of info
  cast_veff_kernel<<<dim3(M / 4), blk, 0, stream>>>(info, vweff, lengths,
                                                    info_hi, info_lo, veff);

  // Gt = Wk @ Wq^T (dual-plane 3-term split) so that Gt^T = G = Wq @ Wk^T
  gemm_bt<128, true, true, 2, 0, false><<<dim3(4, 4, 1), blk, 0, stream>>>(
      Wk_hi, Wk_lo, 512, 0, Wq_hi, Wq_lo, 512, 0, Gt_hi, Gt_lo, 512, 0, 512, nullptr);

  // T = info @ G (dual-plane split out), skip masked row blocks, XCD-swizzled
  gemm_bt<128, true, true, 2, 1, true><<<dim3(4, M / 128, 1), blk, 0, stream>>>(
      info_hi, info_lo, 512, 0, Gt_hi, Gt_lo, 512, 0, T_hi, T_lo, 512, 0, 512, lengths);

  // S[g] = T[g] @ info[g]^T (3-term split -> fp32), tile-skipped, swizzled
  gemm_bt<128, true, true, 0, 3, true><<<dim3(2, 2, GG), blk, 0, stream>>>(
      T_hi, T_lo, 512, 256L * 512, info_hi, info_lo, 512, 256L * 512,
      S, nullptr, 256, 256L * 256, 512, lengths);

  // fused softmax + scorer -> w
  softmax_dot_kernel<<<dim3(M / 4), blk, 0, stream>>>(S, veff, cc, lengths, w);

  // out = einsum('gsl,gl->sg')
  out_kernel<<<dim3(GG, SS / 16), blk, 0, stream>>>(raw, w, lengths, out);
}

// Round 16
// 164.546 us; speedup vs baseline: 1.2704x; 1.0354x over previous
//
#include <hip/hip_runtime.h>
#include <hip/hip_bf16.h>
#include <cstdint>
#include <cmath>

#define GG 128
#define SS 2048
#define LL 256
#define FF 512
#define DD 512

typedef __bf16 bf16_t;
typedef __bf16 bf16x8 __attribute__((ext_vector_type(8)));
typedef __bf16 bf16x4 __attribute__((ext_vector_type(4)));
typedef float  f32x4  __attribute__((ext_vector_type(4)));

#define MiB (1024UL * 1024UL)
// ---------------- workspace layout (~166 MiB peak) ----------------
#define OFF_INFO_HI (0 * MiB)     // bf16 [32768][512]
#define OFF_INFO_LO (32 * MiB)    // bf16 [32768][512]
#define OFF_T_HI    (64 * MiB)    // bf16 [32768][512]
#define OFF_T_LO    (96 * MiB)
#define OFF_S       (128 * MiB)   // fp32 [32768][256] (32 MiB)
#define OFF_WQ_HI   (160 * MiB)
#define OFF_WQ_LO   (160 * MiB + 512 * 1024)
#define OFF_WK_HI   (161 * MiB)
#define OFF_WK_LO   (161 * MiB + 512 * 1024)
#define OFF_GT_HI   (162 * MiB)
#define OFF_GT_LO   (162 * MiB + 512 * 1024)
#define OFF_VEFF    (163 * MiB)   // fp32 [32768]
#define OFF_VW      (164 * MiB)          // fp32 [512] vweff = Wv @ u
#define OFF_CC      (164 * MiB + 4096)   // fp32 [1] folded bias
#define OFF_U       (164 * MiB + 8192)   // fp32 [512]
#define OFF_V34     (164 * MiB + 12288)  // fp32 [128]
#define OFF_T2      (164 * MiB + 12800)  // fp32 [128]
#define OFF_V234    (164 * MiB + 13312)  // fp32 [256]
#define OFF_T3      (164 * MiB + 14336)  // fp32 [64]
#define OFF_WVEC    (165 * MiB)   // fp32 [32768]

// direct-to-LDS 16B load: wave-uniform LDS base + lane*16 implicit
__device__ __forceinline__ void gload16(const bf16_t* g, bf16_t* lds) {
  __builtin_amdgcn_global_load_lds(
      (const __attribute__((address_space(1))) void*)g,
      (__attribute__((address_space(3))) void*)lds, 16, 0, 0);
}

// ---------------------------------------------------------------------------
// merged prep: blocks [0,512) = Wq/Wk split cast;
//              blocks [512,640) = v34[r] = W3[r,:]@W4  (fold stage 1a)
//              blocks [640,768) = t2[c] = b1@W2[:,c] + b2[c] (fold stage 1b)
// ---------------------------------------------------------------------------
__global__ __launch_bounds__(256) void prep_fold1_kernel(
    const float* __restrict__ Wq, const float* __restrict__ Wk,
    const float* __restrict__ W3, const float* __restrict__ W4,
    const float* __restrict__ W2, const float* __restrict__ b1,
    const float* __restrict__ b2,
    bf16_t* __restrict__ Wq_hi, bf16_t* __restrict__ Wq_lo,
    bf16_t* __restrict__ Wk_hi, bf16_t* __restrict__ Wk_lo,
    float* __restrict__ v34, float* __restrict__ t2g) {
  const int b = blockIdx.x, t = threadIdx.x;
  if (b < 512) {
    const float* src = (b < 256) ? Wq : Wk;
    bf16_t* dhi = (b < 256) ? Wq_hi : Wk_hi;
    bf16_t* dlo = (b < 256) ? Wq_lo : Wk_lo;
    int i = (b & 255) * 256 + t;
    float4 v = *(const float4*)&src[(size_t)i * 4];
    float x[4] = {v.x, v.y, v.z, v.w};
    bf16x4 h, l;
#pragma unroll
    for (int e = 0; e < 4; ++e) {
      h[e] = (bf16_t)x[e];
      l[e] = (bf16_t)(x[e] - (float)h[e]);
    }
    *(bf16x4*)&dhi[(size_t)i * 4] = h;
    *(bf16x4*)&dlo[(size_t)i * 4] = l;
    return;
  }
  __shared__ float red[256];
  float acc = 0.f;
  if (b < 640) {  // v34 row-dot, K=64
    const int row = b - 512;
    for (int k = t; k < 64; k += 256) acc += W3[row * 64 + k] * W4[k];
  } else {        // t2 col-dot, K=256
    const int c = b - 640;
    for (int i = t; i < 256; i += 256) acc += b1[i] * W2[(size_t)i * 128 + c];
  }
  red[t] = acc;
  __syncthreads();
  if (t < 128) red[t] += red[t + 128];
  __syncthreads();
  if (t < 64) {
    float a = red[t] + red[t + 64];
#pragma unroll
    for (int off = 32; off > 0; off >>= 1) a += __shfl_down(a, off);
    if (t == 0) {
      if (b < 640) v34[b - 512] = a;
      else t2g[b - 640] = b2[b - 640] + a;
    }
  }
}

// ---------------------------------------------------------------------------
// generic fold stage: block-per-output-element, 256-thread tree reduce.
// ---------------------------------------------------------------------------
__global__ __launch_bounds__(256) void fold2_kernel(
    const float* __restrict__ M0, const float* __restrict__ v0,
    float* __restrict__ out0, int N0, int K0,
    const float* __restrict__ M1, const float* __restrict__ v1,
    const float* __restrict__ bias1, float* __restrict__ out1, int N1, int K1) {
  __shared__ float red[256];
  const int t = threadIdx.x;
  const int b = blockIdx.x;
  float acc = 0.f;
  if (b < N0) {
    const float* row = M0 + (size_t)b * K0;
    for (int k = t; k < K0; k += 256) acc += row[k] * v0[k];
  } else {
    const int c = b - N0;
    for (int i = t; i < K1; i += 256) acc += v1[i] * M1[(size_t)i * N1 + c];
  }
  red[t] = acc;
  __syncthreads();
  if (t < 128) red[t] += red[t + 128];
  __syncthreads();
  if (t < 64) {
    float a = red[t] + red[t + 64];
#pragma unroll
    for (int off = 32; off > 0; off >>= 1) a += __shfl_down(a, off);
    if (t == 0) {
      if (b < N0) out0[b] = a;
      else out1[b - N0] = bias1[b - N0] + a;
    }
  }
}

// ---------------------------------------------------------------------------
// fused info pass: hi/lo split + veff dot. Masked rows get ZERO hi/lo rows
// only where downstream GEMMs actually stage them: rows l in [n,128) always
// (block-0 row tile is always active), rows l in [128,256) only when n>128
// (otherwise both T's SKIP=1 and S's SKIP=3 skip those tiles entirely).
// veff written for all rows. Wave per row.
// ---------------------------------------------------------------------------
__global__ __launch_bounds__(256) void cast_veff_kernel(
    const float* __restrict__ info, const float* __restrict__ vweff,
    const int* __restrict__ lengths, bf16_t* __restrict__ hi,
    bf16_t* __restrict__ lo, float* __restrict__ veff) {
  __shared__ float vw[512];
  const int t = threadIdx.x, lane = t & 63, wv = t >> 6;
  vw[t] = vweff[t];
  vw[256 + t] = vweff[256 + t];
  __syncthreads();
  const int row = blockIdx.x * 4 + wv;
  const int l = row & 255;
  const int n = lengths[row >> 8];
  if (l >= n) {
    if (l < 128 || n > 128) {  // row is staged by an active tile: zero it
      bf16x8 z = {};
      *(bf16x8*)&hi[(size_t)row * 512 + lane * 8] = z;
      *(bf16x8*)&lo[(size_t)row * 512 + lane * 8] = z;
    }
    if (lane == 0) veff[row] = 0.f;
    return;
  }
  const float* ip = info + (size_t)row * 512 + lane * 8;
  const float4 a = *(const float4*)ip;
  const float4 b = *(const float4*)(ip + 4);
  float x[8] = {a.x, a.y, a.z, a.w, b.x, b.y, b.z, b.w};
  bf16x8 h, l8;
#pragma unroll
  for (int e = 0; e < 8; ++e) {
    h[e] = (bf16_t)x[e];
    l8[e] = (bf16_t)(x[e] - (float)h[e]);
  }
  *(bf16x8*)&hi[(size_t)row * 512 + lane * 8] = h;
  *(bf16x8*)&lo[(size_t)row * 512 + lane * 8] = l8;
  const int d0 = lane * 8;
  float acc = 0.f;
#pragma unroll
  for (int e = 0; e < 8; ++e) acc += x[e] * vw[d0 + e];
#pragma unroll
  for (int off = 32; off > 0; off >>= 1) acc += __shfl_down(acc, off);
  if (lane == 0) veff[row] = acc;
}

// ---------------------------------------------------------------------------
// gemm_bt (r9/r12 proven config): C[b] = A[b] @ Bt[b]^T, dual-plane 3-term
// split. BM=128, BK=64, 256 threads (4 waves 2x2), MFMA 16x16x32,
// single-buffer LDS (2 blocks/CU), global_load_lds staging, XOR swizzle on
// SOURCE (rule 21), explicit vmcnt drain before barrier.
// SWIZ: XCD-chunked remap (nwg % 8 == 0).
// OUTMODE: 0 fp32, 2 split bf16. SKIP: 0 none; 1 global-M rows; 3 batched.
// ---------------------------------------------------------------------------
template <int BN, bool ASPLIT, bool BSPLIT, int OUTMODE, int SKIP, bool SWIZ>
__global__ __launch_bounds__(256) void gemm_bt(
    const bf16_t* __restrict__ Ahi, const bf16_t* __restrict__ Alo, int lda, long sA,
    const bf16_t* __restrict__ Bhi, const bf16_t* __restrict__ Blo, int ldb, long sB,
    void* __restrict__ C0, void* __restrict__ C1, int ldc, long sC,
    int K, const int* __restrict__ lengths) {
  constexpr int BM = 128;
  constexpr int BK = 64;
  constexpr int WM = 4;
  constexpr int WN = BN / 32;
  constexpr int PA = BM * BK;
  constexpr int PB = BN * BK;
  constexpr int ITA = BM * 8 / 256;
  constexpr int ITB = BN * 8 / 256;
  __shared__ bf16_t As[(ASPLIT ? 2 : 1) * PA];
  __shared__ bf16_t Bs[(BSPLIT ? 2 : 1) * PB];

  const int gx = gridDim.x, gy = gridDim.y;
  int wgid = blockIdx.x + gx * (blockIdx.y + gy * blockIdx.z);
  if (SWIZ) {
    const int nwg = gx * gy * (int)gridDim.z;
    const int q = nwg >> 3;
    wgid = (wgid & 7) * q + (wgid >> 3);
  }
  const int xx = wgid % gx;
  const int rem = wgid / gx;
  const int yy = rem % gy;
  const int b = rem / gy;
  const int m0 = yy * BM;
  const int n0 = xx * BN;

  if (SKIP == 1) { if ((m0 & 255) >= lengths[m0 >> 8]) return; }
  if (SKIP == 3) { int n = lengths[b]; if (m0 >= n || n0 >= n) return; }

  const int t = threadIdx.x;
  const int lane = t & 63;
  const int wave = t >> 6;
  const int wm = (wave >> 1) * 64;
  const int wn = (wave & 1) * (BN / 2);

  const bf16_t* Ah = Ahi + (size_t)b * sA;
  const bf16_t* Al = ASPLIT ? Alo + (size_t)b * sA : nullptr;
  const bf16_t* Bh = Bhi + (size_t)b * sB;
  const bf16_t* Bl = BSPLIT ? Blo + (size_t)b * sB : nullptr;

  f32x4 acc[WM][WN];
#pragma unroll
  for (int i = 0; i < WM; ++i)
#pragma unroll
    for (int j = 0; j < WN; ++j) acc[i][j] = {0.f, 0.f, 0.f, 0.f};

  const int fr = lane & 15;
  const int fs = lane >> 4;
  const int sr = t >> 3, ssl = t & 7;

  for (int k0 = 0; k0 < K; k0 += BK) {
#pragma unroll
    for (int it = 0; it < ITA; ++it) {
      const int r = sr + it * 32;
      const size_t ga = (size_t)(m0 + r) * lda + k0 + ((ssl ^ (r & 7)) << 3);
      bf16_t* dst = &As[(it * 256 + wave * 64) * 8];
      gload16(&Ah[ga], dst);
      if (ASPLIT) gload16(&Al[ga], dst + PA);
    }
#pragma unroll
    for (int it = 0; it < ITB; ++it) {
      const int r = sr + it * 32;
      const size_t ga = (size_t)(n0 + r) * ldb + k0 + ((ssl ^ (r & 7)) << 3);
      bf16_t* dst = &Bs[(it * 256 + wave * 64) * 8];
      gload16(&Bh[ga], dst);
      if (BSPLIT) gload16(&Bl[ga], dst + PB);
    }
    asm volatile("s_waitcnt vmcnt(0)" ::: "memory");
    __builtin_amdgcn_sched_barrier(0);
    __syncthreads();
#pragma unroll
    for (int kk = 0; kk < 2; ++kk) {
      bf16x8 ah[WM], al[WM], bh[WN], bl[WN];
#pragma unroll
      for (int i = 0; i < WM; ++i) {
        int r = wm + i * 16 + fr;
        int la = r * BK + (((kk * 4 + fs) ^ (r & 7)) * 8);
        ah[i] = *(const bf16x8*)&As[la];
        if (ASPLIT) al[i] = *(const bf16x8*)&As[PA + la];
      }
#pragma unroll
      for (int j = 0; j < WN; ++j) {
        int r = wn + j * 16 + fr;
        int la = r * BK + (((kk * 4 + fs) ^ (r & 7)) * 8);
        bh[j] = *(const bf16x8*)&Bs[la];
        if (BSPLIT) bl[j] = *(const bf16x8*)&Bs[PB + la];
      }
#pragma unroll
      for (int i = 0; i < WM; ++i)
#pragma unroll
        for (int j = 0; j < WN; ++j) {
          acc[i][j] = __builtin_amdgcn_mfma_f32_16x16x32_bf16(ah[i], bh[j], acc[i][j], 0, 0, 0);
          if (BSPLIT)
            acc[i][j] = __builtin_amdgcn_mfma_f32_16x16x32_bf16(ah[i], bl[j], acc[i][j], 0, 0, 0);
          if (ASPLIT)
            acc[i][j] = __builtin_amdgcn_mfma_f32_16x16x32_bf16(al[i], bh[j], acc[i][j], 0, 0, 0);
        }
    }
    __syncthreads();
  }

#pragma unroll
  for (int i = 0; i < WM; ++i) {
#pragma unroll
    for (int j = 0; j < WN; ++j) {
      const int col = n0 + wn + j * 16 + fr;
#pragma unroll
      for (int jj = 0; jj < 4; ++jj) {
        const int row = m0 + wm + i * 16 + fs * 4 + jj;
        const float v = acc[i][j][jj];
        const size_t off = (size_t)b * sC + (size_t)row * ldc + col;
        if (OUTMODE == 0) {
          ((float*)C0)[off] = v;
        } else {
          bf16_t h = (bf16_t)v;
          ((bf16_t*)C0)[off] = h;
          ((bf16_t*)C1)[off] = (bf16_t)(v - (float)h);
        }
      }
    }
  }
}

// ---------------------------------------------------------------------------
// fused masked softmax + scorer: w[row] = sum(exp(S-m)*veff)/sum(exp) + c0,
// with length==1 onehot and masking. One wave per row; all w written.
// ---------------------------------------------------------------------------
__global__ __launch_bounds__(256) void softmax_dot_kernel(
    const float* __restrict__ S, const float* __restrict__ veff,
    const float* __restrict__ cc, const int* __restrict__ lengths,
    float* __restrict__ w) {
  const int t = threadIdx.x, lane = t & 63, wave = t >> 6;
  const int row = blockIdx.x * 4 + wave;
  const int g = row >> 8, l = row & 255;
  const int n = lengths[g];
  if (n == 1 || l >= n) {
    if (lane == 0) w[row] = (n == 1 && l == 0) ? 1.f : 0.f;
    return;
  }
  const float* srow = S + (size_t)row * 256;
  const int c0i = lane * 4;
  float4 v = *(const float4*)&srow[c0i];
  float4 vf = *(const float4*)&veff[g * 256 + c0i];
  float s[4] = {v.x, v.y, v.z, v.w};
  float ve[4] = {vf.x, vf.y, vf.z, vf.w};
  float m = -INFINITY;
#pragma unroll
  for (int e = 0; e < 4; ++e)
    if (c0i + e < n) m = fmaxf(m, s[e]);
#pragma unroll
  for (int off = 32; off > 0; off >>= 1) m = fmaxf(m, __shfl_xor(m, off));
  float sum = 0.f, dot = 0.f;
#pragma unroll
  for (int e = 0; e < 4; ++e) {
    if (c0i + e < n) {
      float ee = __expf(s[e] - m);
      sum += ee;
      dot += ee * ve[e];
    }
  }
#pragma unroll
  for (int off = 32; off > 0; off >>= 1) {
    sum += __shfl_xor(sum, off);
    dot += __shfl_xor(dot, off);
  }
  if (lane == 0) w[row] = dot / sum + cc[0];
}

// ---------------------------------------------------------------------------
// out[s,g] = sum_l raw[g,s,l] * w[g,l]; skips l >= n (w is exactly 0 there).
// 64 samples per block (16 per wave) — amortizes the LDS w-row staging and
// cuts dispatch overhead (the r15 lever, extended).
// ---------------------------------------------------------------------------
__global__ __launch_bounds__(256) void out_kernel(
    const float* __restrict__ raw, const float* __restrict__ w,
    const int* __restrict__ lengths, float* __restrict__ out) {
  __shared__ float wl[LL];
  const int g = blockIdx.x;
  const int t = threadIdx.x;
  wl[t] = w[g * LL + t];
  __syncthreads();
  const int n = lengths[g];
  const int wave = t >> 6, lane = t & 63;
  const bool act = lane * 4 < n;
  float4 w4v = make_float4(0.f, 0.f, 0.f, 0.f);
  if (act) w4v = *(const float4*)&wl[lane * 4];
  const int s0 = blockIdx.y * 64 + wave * 16;
#pragma unroll 4
  for (int e = 0; e < 16; ++e) {
    const int s = s0 + e;
    float acc = 0.f;
    if (act) {
      const float4 r4 = *(const float4*)(raw + ((size_t)g * SS + s) * LL + lane * 4);
      acc = r4.x * w4v.x + r4.y * w4v.y + r4.z * w4v.z + r4.w * w4v.w;
    }
#pragma unroll
    for (int off = 32; off > 0; off >>= 1) acc += __shfl_down(acc, off);
    if (lane == 0) out[(size_t)s * GG + g] = acc;
  }
}

// ---------------------------------------------------------------------------
extern "C" void kernel_launch(void* const* d_in, const int* in_sizes, int n_in,
                              void* d_out, int out_size, void* d_ws, size_t ws_size,
                              hipStream_t stream) {
  const float* raw  = (const float*)d_in[0];
  const float* info = (const float*)d_in[1];
  const float* Wq   = (const float*)d_in[2];
  const float* Wk   = (const float*)d_in[3];
  const float* Wv   = (const float*)d_in[4];
  const float* W1   = (const float*)d_in[5];
  const float* b1   = (const float*)d_in[6];
  const float* W2   = (const float*)d_in[7];
  const float* b2   = (const float*)d_in[8];
  const float* W3   = (const float*)d_in[9];
  const float* b3   = (const float*)d_in[10];
  const float* W4   = (const float*)d_in[11];
  const float* b4   = (const float*)d_in[12];
  const int* lengths = (const int*)d_in[13];
  float* out = (float*)d_out;

  char* ws = (char*)d_ws;
  bf16_t* info_hi = (bf16_t*)(ws + OFF_INFO_HI);
  bf16_t* info_lo = (bf16_t*)(ws + OFF_INFO_LO);
  bf16_t* T_hi = (bf16_t*)(ws + OFF_T_HI);
  bf16_t* T_lo = (bf16_t*)(ws + OFF_T_LO);
  bf16_t* Wq_hi = (bf16_t*)(ws + OFF_WQ_HI);
  bf16_t* Wq_lo = (bf16_t*)(ws + OFF_WQ_LO);
  bf16_t* Wk_hi = (bf16_t*)(ws + OFF_WK_HI);
  bf16_t* Wk_lo = (bf16_t*)(ws + OFF_WK_LO);
  bf16_t* Gt_hi = (bf16_t*)(ws + OFF_GT_HI);
  bf16_t* Gt_lo = (bf16_t*)(ws + OFF_GT_LO);
  float*  S     = (float*)(ws + OFF_S);
  float*  veff  = (float*)(ws + OFF_VEFF);
  float*  vweff = (float*)(ws + OFF_VW);
  float*  cc    = (float*)(ws + OFF_CC);
  float*  u_g   = (float*)(ws + OFF_U);
  float*  v34   = (float*)(ws + OFF_V34);
  float*  t2g   = (float*)(ws + OFF_T2);
  float*  v234  = (float*)(ws + OFF_V234);
  float*  t3g   = (float*)(ws + OFF_T3);
  float*  w     = (float*)(ws + OFF_WVEC);

  dim3 blk(256);
  const int M = GG * LL;  // 32768

  // merged prep: Wq/Wk split cast + fold stage 1 (v34, t2)
  prep_fold1_kernel<<<dim3(768), blk, 0, stream>>>(
      Wq, Wk, W3, W4, W2, b1, b2, Wq_hi, Wq_lo, Wk_hi, Wk_lo, v34, t2g);

  // fold stages 2-4
  fold2_kernel<<<dim3(320), blk, 0, stream>>>(
      W2, v34, v234, 256, 128, W3, t2g, b3, t3g, 64, 128);
  fold2_kernel<<<dim3(513), blk, 0, stream>>>(
      W1, v234, u_g, 512, 256, W4, t3g, b4, cc, 1, 64);
  fold2_kernel<<<dim3(512), blk, 0, stream>>>(
      Wv, u_g, vweff, 512, 512, W4, t3g, b4, cc, 0, 64);

  // fused info pass: hi/lo split + veff in one read of info
  cast_veff_kernel<<<dim3(M / 4), blk, 0, stream>>>(info, vweff, lengths,
                                                    info_hi, info_lo, veff);

  // Gt = Wk @ Wq^T (dual-plane 3-term split) so that Gt^T = G = Wq @ Wk^T
  gemm_bt<128, true, true, 2, 0, false><<<dim3(4, 4, 1), blk, 0, stream>>>(
      Wk_hi, Wk_lo, 512, 0, Wq_hi, Wq_lo, 512, 0, Gt_hi, Gt_lo, 512, 0, 512, nullptr);

  // T = info @ G (dual-plane split out), skip masked row blocks, XCD-swizzled
  gemm_bt<128, true, true, 2, 1, true><<<dim3(4, M / 128, 1), blk, 0, stream>>>(
      info_hi, info_lo, 512, 0, Gt_hi, Gt_lo, 512, 0, T_hi, T_lo, 512, 0, 512, lengths);

  // S[g] = T[g] @ info[g]^T (3-term split -> fp32), tile-skipped, swizzled
  gemm_bt<128, true, true, 0, 3, true><<<dim3(2, 2, GG), blk, 0, stream>>>(
      T_hi, T_lo, 512, 256L * 512, info_hi, info_lo, 512, 256L * 512,
      S, nullptr, 256, 256L * 256, 512, lengths);

  // fused softmax + scorer -> w
  softmax_dot_kernel<<<dim3(M / 4), blk, 0, stream>>>(S, veff, cc, lengths, w);

  // out = einsum('gsl,gl->sg')
  out_kernel<<<dim3(GG, SS / 64), blk, 0, stream>>>(raw, w, lengths, out);
}